// Round 10
// baseline (141.581 us; speedup 1.0000x reference)
//
#include <hip/hip_runtime.h>

// ============================================================================
// R10: ZERO-barrier k-loop. A operand read per-wave directly from X
// (8 dwordx4/tile, 16 full 64B lines each; 3/4 waves L1-hit) and converted
// in-register -> lds_A, all 8 GBARs, and group convert phases DELETED.
// B: wave-private DMA double-buffer (R9-verified). Uniform vmcnt(8)/tile:
// outstanding at TILE(T) = {B(T),Xa(T),B(T+1)}; vmcnt(8) retires B(T)+Xa(T).
// Waves fully independent until the single epilogue barrier.
// Diagnosis R9: 114.7us best; residual = A-group barrier convoy (8 GBARs).
// ============================================================================

#define D_IN   1024
#define D_PROJ 256
#define N_C    64
#define N_ROWS 16384
#define BM     32
#define BK     64
#define Z_STRIDE 264        // D_PROJ + 8 pad

typedef float v4f __attribute__((ext_vector_type(4)));
typedef short v8s __attribute__((ext_vector_type(8)));

__device__ inline unsigned short f2bf(float f) {
  unsigned int u = __float_as_uint(f);
  u = u + 0x7fffu + ((u >> 16) & 1u);   // round-to-nearest-even
  return (unsigned short)(u >> 16);
}

__device__ inline void async16(const void* g, void* s) {
  __builtin_amdgcn_global_load_lds(
      (const __attribute__((address_space(1))) unsigned int*)g,
      (__attribute__((address_space(3))) unsigned int*)s, 16, 0, 0);
}

// lgkm-only barrier: pb/global loads stay in flight
#define GBAR() do {                                              \
  asm volatile("s_waitcnt lgkmcnt(0)" ::: "memory");             \
  __builtin_amdgcn_s_barrier();                                  \
  __builtin_amdgcn_sched_barrier(0);                             \
} while (0)

// ---------------------------------------------------------------------------
// Prep (unchanged): projT bf16 [256][1024], protoB bf16 [64][256], pnorm2[64],
// mu_p[256] = mean @ proj
// ---------------------------------------------------------------------------
__global__ __launch_bounds__(256) void prep_kernel(
    const float* __restrict__ proj,      // [1024][256]
    const float* __restrict__ protos,    // [64][256]
    const float* __restrict__ mean,      // [1024]
    unsigned short* __restrict__ projT,  // [256][1024]
    unsigned short* __restrict__ protoB, // [64][256]
    float* __restrict__ pnorm2,          // [64]
    float* __restrict__ mu_p)            // [256]
{
  __shared__ float tile[64][65];
  __shared__ float part[16][17];
  const int b = blockIdx.x;
  const int t = threadIdx.x;
  if (b < 64) {
    const int k0 = (b & 15) * 64, n0 = (b >> 4) * 64;
    const int r = t >> 4, c4 = (t & 15) * 4;
    for (int rr = r; rr < 64; rr += 16) {
      const float4 v = *(const float4*)(proj + (k0 + rr) * D_PROJ + n0 + c4);
      tile[rr][c4 + 0] = v.x; tile[rr][c4 + 1] = v.y;
      tile[rr][c4 + 2] = v.z; tile[rr][c4 + 3] = v.w;
    }
    __syncthreads();
    const int n = t >> 2, kc = (t & 3) * 16;
    unsigned short o[16];
#pragma unroll
    for (int i = 0; i < 16; ++i) o[i] = f2bf(tile[kc + i][n]);
    unsigned short* dst = projT + (n0 + n) * D_IN + k0 + kc;
#pragma unroll
    for (int i = 0; i < 4; ++i) {
      ushort4 s4 = { o[4*i+0], o[4*i+1], o[4*i+2], o[4*i+3] };
      *(ushort4*)(dst + 4*i) = s4;
    }
  } else if (b < 80) {
    const int w = t >> 6, l = t & 63;
    const int c = (b - 64) * 4 + w;                    // proto 0..63
    const float4 v = *(const float4*)(protos + c * D_PROJ + l * 4);
    float ss = v.x*v.x + v.y*v.y + v.z*v.z + v.w*v.w;
#pragma unroll
    for (int m = 1; m < 64; m <<= 1) ss += __shfl_xor(ss, m);
    if (l == 0) pnorm2[c] = ss;
    ushort4 o = { f2bf(v.x), f2bf(v.y), f2bf(v.z), f2bf(v.w) };
    *(ushort4*)(protoB + c * D_PROJ + l * 4) = o;
  } else {
    const int b2  = b - 80;
    const int col = b2 * 16 + (t & 15);
    const int ks  = t >> 4;
    float s = 0.0f;
    const int kb = ks * 64;
#pragma unroll 4
    for (int k = 0; k < 64; ++k)
      s = fmaf(mean[kb + k], proj[(kb + k) * D_PROJ + col], s);
    part[ks][t & 15] = s;
    __syncthreads();
    if (t < 16) {
      float acc = 0.0f;
#pragma unroll
      for (int i = 0; i < 16; ++i) acc += part[i][t];
      mu_p[b2 * 16 + t] = acc;
    }
  }
}

// ---------------------------------------------------------------------------
// Main: 32 rows/block, 512 blocks (2/CU), 256 threads (4 independent waves).
// Wave w: rows 0..31 x cols w*64..+63. Per tile: vmcnt(8); cvt A frags from
// xa regs; 8 B ds_read + 16 MFMA; lgkm(0); load Xa(T+1) [8 dwordx4 from X];
// stage B(T+2) [8 DMA]. No barriers until the epilogue.
// ---------------------------------------------------------------------------
__global__ __launch_bounds__(256, 2) void protonet_main(
    const float* __restrict__ X,               // [16384][1024]
    const unsigned short* __restrict__ projT,  // [256][1024] bf16
    const unsigned short* __restrict__ protoB, // [64][256]   bf16
    const float* __restrict__ pnorm2,          // [64]
    const float* __restrict__ mu_p,            // [256]
    float* __restrict__ out)                   // [16384][64]
{
  __shared__ unsigned short lds_B[32768];   // 64 KB: 2 bufs x 4 wave-quarters
  __shared__ float lds_part[4][BM];
  __shared__ float lds_inv[BM];
  __shared__ float lds_z2[BM];

  const int t  = threadIdx.x;
  const int w  = t >> 6;        // wave 0..3
  const int l  = t & 63;
  const int q  = l >> 4;
  const int lc = l & 15;
  const int row0 = blockIdx.x * BM;

  // B DMA src: instr s covers projT rows w*64+s*8..+7; lane l -> +(l>>3);
  // phys chunk l&7 holds logical (l&7)^(row&7) via pre-swizzled source.
  const int bsrc0 = ((w << 6) + (l >> 3)) * D_IN + (((l & 7) ^ ((l >> 3) & 7)) << 3);

  // A direct-load bases: lane (lc,q) -> rows row0+lc / row0+16+lc, k = q*8
  const float* xA0 = X + (row0 + lc) * D_IN + (q << 3);
  const float* xA1 = X + (row0 + 16 + lc) * D_IN + (q << 3);

  float4 xa[2][8];     // A fp32 in flight: [tile&1][frag*4 + kk*2 + half]
  v4f acc1[8];         // [rg*4+j]: rows rg*16.. x cols w*64+j*16..
#pragma unroll
  for (int j = 0; j < 8; ++j) acc1[j] = (v4f)(0.0f);

#define STAGEB(T) do {                                                    \
    _Pragma("unroll")                                                     \
    for (int s_ = 0; s_ < 8; ++s_)                                        \
      async16(projT + bsrc0 + s_ * (8 * D_IN) + (T) * BK,                 \
              lds_B + (((((T) & 1) << 2) | w) << 12) + (s_ << 9));        \
  } while (0)

#define XALOAD(T) do {                                                   \
    const float* x0_ = xA0 + ((T) << 6);                                 \
    const float* x1_ = xA1 + ((T) << 6);                                 \
    xa[(T) & 1][0] = *(const float4*)(x0_);                              \
    xa[(T) & 1][1] = *(const float4*)(x0_ + 4);                          \
    xa[(T) & 1][2] = *(const float4*)(x0_ + 32);                         \
    xa[(T) & 1][3] = *(const float4*)(x0_ + 36);                         \
    xa[(T) & 1][4] = *(const float4*)(x1_);                              \
    xa[(T) & 1][5] = *(const float4*)(x1_ + 4);                          \
    xa[(T) & 1][6] = *(const float4*)(x1_ + 32);                         \
    xa[(T) & 1][7] = *(const float4*)(x1_ + 36);                         \
  } while (0)

#define CVT8(dst, va, vb) do {                                           \
    dst[0] = (short)f2bf((va).x); dst[1] = (short)f2bf((va).y);          \
    dst[2] = (short)f2bf((va).z); dst[3] = (short)f2bf((va).w);          \
    dst[4] = (short)f2bf((vb).x); dst[5] = (short)f2bf((vb).y);          \
    dst[6] = (short)f2bf((vb).z); dst[7] = (short)f2bf((vb).w);          \
  } while (0)

#define MFMA_ __builtin_amdgcn_mfma_f32_16x16x32_bf16
#define KSTEP(T, KK, ALO, AHI) do {                                      \
    const int po_ = ((((KK) << 2) + q) ^ (lc & 7)) << 3;                 \
    const unsigned short* Bq_ = lds_B + (((((T) & 1) << 2) | w) << 12);  \
    v8s b0_ = *(const v8s*)(Bq_ + (lc << 6) + po_);                      \
    v8s b1_ = *(const v8s*)(Bq_ + 1024 + (lc << 6) + po_);               \
    v8s b2_ = *(const v8s*)(Bq_ + 2048 + (lc << 6) + po_);               \
    v8s b3_ = *(const v8s*)(Bq_ + 3072 + (lc << 6) + po_);               \
    acc1[0] = MFMA_(ALO, b0_, acc1[0], 0, 0, 0);                         \
    acc1[1] = MFMA_(ALO, b1_, acc1[1], 0, 0, 0);                         \
    acc1[2] = MFMA_(ALO, b2_, acc1[2], 0, 0, 0);                         \
    acc1[3] = MFMA_(ALO, b3_, acc1[3], 0, 0, 0);                         \
    acc1[4] = MFMA_(AHI, b0_, acc1[4], 0, 0, 0);                         \
    acc1[5] = MFMA_(AHI, b1_, acc1[5], 0, 0, 0);                         \
    acc1[6] = MFMA_(AHI, b2_, acc1[6], 0, 0, 0);                         \
    acc1[7] = MFMA_(AHI, b3_, acc1[7], 0, 0, 0);                         \
  } while (0)

// TILE: vmcnt(V) retires B(T)+Xa(T) (B(T+1) is the 8 newest; compiler's own
// reg-tracking re-checks xa). lgkm(0) before STAGEB: this wave's ds_reads of
// buf (T&1) are fully done before the DMA that overwrites it is issued.
#define TILE(T, V) do {                                                  \
    asm volatile("s_waitcnt vmcnt(" #V ")" ::: "memory");                \
    __builtin_amdgcn_sched_barrier(0);                                   \
    v8s a00_, a01_, a10_, a11_;                                          \
    CVT8(a00_, xa[(T) & 1][0], xa[(T) & 1][1]);                          \
    CVT8(a01_, xa[(T) & 1][2], xa[(T) & 1][3]);                          \
    CVT8(a10_, xa[(T) & 1][4], xa[(T) & 1][5]);                          \
    CVT8(a11_, xa[(T) & 1][6], xa[(T) & 1][7]);                          \
    KSTEP(T, 0, a00_, a10_);                                             \
    KSTEP(T, 1, a01_, a11_);                                             \
    asm volatile("s_waitcnt lgkmcnt(0)" ::: "memory");                   \
    __builtin_amdgcn_sched_barrier(0);                                   \
    if ((T) < 15) XALOAD((T) + 1);                                       \
    if ((T) + 2 <= 15) STAGEB((T) + 2);                                  \
  } while (0)

  // ---- prologue: Xa(0), B(0), B(1) ----
  XALOAD(0);
  STAGEB(0);
  STAGEB(1);

  // ---- barrier-free k-loop ----
  TILE(0, 8);  TILE(1, 8);  TILE(2, 8);  TILE(3, 8);
  TILE(4, 8);  TILE(5, 8);  TILE(6, 8);  TILE(7, 8);
  TILE(8, 8);  TILE(9, 8);  TILE(10, 8); TILE(11, 8);
  TILE(12, 8); TILE(13, 8); TILE(14, 8); TILE(15, 0);

  // ---- GEMM2 proto loads issued now (stay in flight across GBAR) ----
  v8s pb[8];
  {
    const unsigned short* prow = protoB + ((w << 4) + lc) * D_PROJ + (q << 3);
#pragma unroll
    for (int kk = 0; kk < 8; ++kk)
      pb[kk] = *(const v8s*)(prow + (kk << 5));
  }

  GBAR();   // all waves done reading lds_B (each drained lgkm in TILE(15))

  // ---- Zc = Zraw - mu_p -> Z (aliases lds_B) + fp32 row norms ----
  unsigned short* lds_Z = lds_B;      // 8448 shorts = 16.5 KB
  float mu[4];
#pragma unroll
  for (int j = 0; j < 4; ++j) mu[j] = mu_p[(w << 6) + (j << 4) + lc];
#pragma unroll
  for (int rg = 0; rg < 2; ++rg) {
#pragma unroll
    for (int r = 0; r < 4; ++r) {
      const int row = (rg << 4) + (q << 2) + r;
      float s2 = 0.0f;
#pragma unroll
      for (int j = 0; j < 4; ++j) {
        const float v = acc1[rg * 4 + j][r] - mu[j];
        s2 += v * v;
        lds_Z[row * Z_STRIDE + (w << 6) + (j << 4) + lc] = f2bf(v);
      }
      s2 += __shfl_xor(s2, 1);
      s2 += __shfl_xor(s2, 2);
      s2 += __shfl_xor(s2, 4);
      s2 += __shfl_xor(s2, 8);
      if (lc == 0) lds_part[w][row] = s2;
    }
  }
  __syncthreads();
  if (t < BM) {
    const float n2 = lds_part[0][t] + lds_part[1][t] +
                     lds_part[2][t] + lds_part[3][t];
    const float nrm = sqrtf(n2);
    const float inv = 1.0f / fmaxf(nrm, 1e-12f);   // torch/jax normalize eps
    lds_inv[t] = inv;
    lds_z2[t]  = n2 * inv * inv;                   // == 1 unless degenerate
  }
  __syncthreads();

  // ---- GEMM2: dot(Zc, proto_c); wave w: 32 rows x protos w*16..+15 ----
  v4f acc2[2] = { (v4f)(0.0f), (v4f)(0.0f) };
#pragma unroll
  for (int kk = 0; kk < 8; ++kk) {
#pragma unroll
    for (int sr = 0; sr < 2; ++sr) {
      v8s za = *(const v8s*)(lds_Z + ((sr << 4) + lc) * Z_STRIDE +
                             (kk << 5) + (q << 3));
      acc2[sr] = MFMA_(za, pb[kk], acc2[sr], 0, 0, 0);
    }
  }

  // ---- epilogue: d^2 = ||Z||^2 + ||p||^2 - 2*dot*inv ; score = -sqrt(d^2) ----
  const int c  = (w << 4) + lc;
  const float pn = pnorm2[c];
#pragma unroll
  for (int sr = 0; sr < 2; ++sr) {
#pragma unroll
    for (int r = 0; r < 4; ++r) {
      const int row = (sr << 4) + (q << 2) + r;
      const float inv = lds_inv[row];
      const float d2  = lds_z2[row] + pn - 2.0f * acc2[sr][r] * inv;
      out[(row0 + row) * N_C + c] = -sqrtf(fmaxf(d2, 0.0f));
    }
  }
}

extern "C" void kernel_launch(void* const* d_in, const int* in_sizes, int n_in,
                              void* d_out, int out_size, void* d_ws, size_t ws_size,
                              hipStream_t stream) {
  const float* X      = (const float*)d_in[0];
  const float* protos = (const float*)d_in[1];
  const float* mean   = (const float*)d_in[2];
  const float* proj   = (const float*)d_in[3];
  float* out = (float*)d_out;

  unsigned short* projT  = (unsigned short*)d_ws;          // 256*1024 bf16 = 512 KB
  unsigned short* protoB = projT + D_PROJ * D_IN;          // 64*256  bf16 = 32 KB
  float*          pn2    = (float*)(protoB + N_C * D_PROJ);// 64 fp32
  float*          mup    = pn2 + N_C;                      // 256 fp32

  prep_kernel<<<96, 256, 0, stream>>>(proj, protos, mean, projT, protoB, pn2, mup);
  protonet_main<<<N_ROWS / BM, 256, 0, stream>>>(X, projT, protoB, pn2, mup, out);
}

// Round 11
// 137.776 us; speedup vs baseline: 1.0276x; 1.0276x over previous
//
#include <hip/hip_runtime.h>

// ============================================================================
// R11: R10's zero-barrier k-loop + 3-tile-deep X prefetch ring.
// Diagnosis R10 (counters): occupancy 31->17%, main 57us — X loaded only
// 1 tile ahead -> per-tile HBM latency (~800cy) exposed on the critical path
// (R9/R2 loaded X a 4-tile group ahead and never paid it). Fix: xa[3][8]
// ring (Xa(T) issued at tile T-3), B-before-Xa issue order per tile (vmcnt
// is in-order: B(T) wait must not force-retire younger Xa prefetches),
// uniform vmcnt(24) ledger. + T5 setprio(1) around MFMA (barrier-free waves
// -> scheduler has role diversity to arbitrate).
// ============================================================================

#define D_IN   1024
#define D_PROJ 256
#define N_C    64
#define N_ROWS 16384
#define BM     32
#define BK     64
#define Z_STRIDE 264        // D_PROJ + 8 pad

typedef float v4f __attribute__((ext_vector_type(4)));
typedef short v8s __attribute__((ext_vector_type(8)));

__device__ inline unsigned short f2bf(float f) {
  unsigned int u = __float_as_uint(f);
  u = u + 0x7fffu + ((u >> 16) & 1u);   // round-to-nearest-even
  return (unsigned short)(u >> 16);
}

__device__ inline void async16(const void* g, void* s) {
  __builtin_amdgcn_global_load_lds(
      (const __attribute__((address_space(1))) unsigned int*)g,
      (__attribute__((address_space(3))) unsigned int*)s, 16, 0, 0);
}

// lgkm-only barrier: global loads stay in flight
#define GBAR() do {                                              \
  asm volatile("s_waitcnt lgkmcnt(0)" ::: "memory");             \
  __builtin_amdgcn_s_barrier();                                  \
  __builtin_amdgcn_sched_barrier(0);                             \
} while (0)

// ---------------------------------------------------------------------------
// Prep (unchanged): projT bf16 [256][1024], protoB bf16 [64][256], pnorm2[64],
// mu_p[256] = mean @ proj
// ---------------------------------------------------------------------------
__global__ __launch_bounds__(256) void prep_kernel(
    const float* __restrict__ proj,      // [1024][256]
    const float* __restrict__ protos,    // [64][256]
    const float* __restrict__ mean,      // [1024]
    unsigned short* __restrict__ projT,  // [256][1024]
    unsigned short* __restrict__ protoB, // [64][256]
    float* __restrict__ pnorm2,          // [64]
    float* __restrict__ mu_p)            // [256]
{
  __shared__ float tile[64][65];
  __shared__ float part[16][17];
  const int b = blockIdx.x;
  const int t = threadIdx.x;
  if (b < 64) {
    const int k0 = (b & 15) * 64, n0 = (b >> 4) * 64;
    const int r = t >> 4, c4 = (t & 15) * 4;
    for (int rr = r; rr < 64; rr += 16) {
      const float4 v = *(const float4*)(proj + (k0 + rr) * D_PROJ + n0 + c4);
      tile[rr][c4 + 0] = v.x; tile[rr][c4 + 1] = v.y;
      tile[rr][c4 + 2] = v.z; tile[rr][c4 + 3] = v.w;
    }
    __syncthreads();
    const int n = t >> 2, kc = (t & 3) * 16;
    unsigned short o[16];
#pragma unroll
    for (int i = 0; i < 16; ++i) o[i] = f2bf(tile[kc + i][n]);
    unsigned short* dst = projT + (n0 + n) * D_IN + k0 + kc;
#pragma unroll
    for (int i = 0; i < 4; ++i) {
      ushort4 s4 = { o[4*i+0], o[4*i+1], o[4*i+2], o[4*i+3] };
      *(ushort4*)(dst + 4*i) = s4;
    }
  } else if (b < 80) {
    const int w = t >> 6, l = t & 63;
    const int c = (b - 64) * 4 + w;                    // proto 0..63
    const float4 v = *(const float4*)(protos + c * D_PROJ + l * 4);
    float ss = v.x*v.x + v.y*v.y + v.z*v.z + v.w*v.w;
#pragma unroll
    for (int m = 1; m < 64; m <<= 1) ss += __shfl_xor(ss, m);
    if (l == 0) pnorm2[c] = ss;
    ushort4 o = { f2bf(v.x), f2bf(v.y), f2bf(v.z), f2bf(v.w) };
    *(ushort4*)(protoB + c * D_PROJ + l * 4) = o;
  } else {
    const int b2  = b - 80;
    const int col = b2 * 16 + (t & 15);
    const int ks  = t >> 4;
    float s = 0.0f;
    const int kb = ks * 64;
#pragma unroll 4
    for (int k = 0; k < 64; ++k)
      s = fmaf(mean[kb + k], proj[(kb + k) * D_PROJ + col], s);
    part[ks][t & 15] = s;
    __syncthreads();
    if (t < 16) {
      float acc = 0.0f;
#pragma unroll
      for (int i = 0; i < 16; ++i) acc += part[i][t];
      mu_p[b2 * 16 + t] = acc;
    }
  }
}

// ---------------------------------------------------------------------------
// Main: 32 rows/block, 512 blocks (2/CU), 256 threads (4 independent waves).
// Wave w: rows 0..31 x cols w*64..+63.
// Per tile T: vmcnt(24) [retires Xa(T),B(T); leaves Xa(T+1),B(T+1),Xa(T+2)];
//   setprio(1); cvt A; 8 B ds_read + 16 MFMA; setprio(0); lgkm(0);
//   STAGEB(T+2); XALOAD(T+3).   No barriers until the epilogue.
// ---------------------------------------------------------------------------
__global__ __launch_bounds__(256, 2) void protonet_main(
    const float* __restrict__ X,               // [16384][1024]
    const unsigned short* __restrict__ projT,  // [256][1024] bf16
    const unsigned short* __restrict__ protoB, // [64][256]   bf16
    const float* __restrict__ pnorm2,          // [64]
    const float* __restrict__ mu_p,            // [256]
    float* __restrict__ out)                   // [16384][64]
{
  __shared__ unsigned short lds_B[32768];   // 64 KB: 2 bufs x 4 wave-quarters
  __shared__ float lds_part[4][BM];
  __shared__ float lds_inv[BM];
  __shared__ float lds_z2[BM];

  const int t  = threadIdx.x;
  const int w  = t >> 6;        // wave 0..3
  const int l  = t & 63;
  const int q  = l >> 4;
  const int lc = l & 15;
  const int row0 = blockIdx.x * BM;

  // B DMA src: instr s covers projT rows w*64+s*8..+7; lane l -> +(l>>3);
  // phys chunk l&7 holds logical (l&7)^(row&7) via pre-swizzled source.
  const int bsrc0 = ((w << 6) + (l >> 3)) * D_IN + (((l & 7) ^ ((l >> 3) & 7)) << 3);

  // A direct-load bases: lane (lc,q) -> rows row0+lc / row0+16+lc, k = q*8
  const float* xA0 = X + (row0 + lc) * D_IN + (q << 3);
  const float* xA1 = X + (row0 + 16 + lc) * D_IN + (q << 3);

  float4 xa[3][8];     // A fp32 ring, 3 tiles deep (96 VGPR)
  v4f acc1[8];         // [rg*4+j]: rows rg*16.. x cols w*64+j*16..
#pragma unroll
  for (int j = 0; j < 8; ++j) acc1[j] = (v4f)(0.0f);

#define STAGEB(T) do {                                                    \
    _Pragma("unroll")                                                     \
    for (int s_ = 0; s_ < 8; ++s_)                                        \
      async16(projT + bsrc0 + s_ * (8 * D_IN) + (T) * BK,                 \
              lds_B + (((((T) & 1) << 2) | w) << 12) + (s_ << 9));        \
  } while (0)

#define XALOAD(T) do {                                                   \
    const float* x0_ = xA0 + ((T) << 6);                                 \
    const float* x1_ = xA1 + ((T) << 6);                                 \
    xa[(T) % 3][0] = *(const float4*)(x0_);                              \
    xa[(T) % 3][1] = *(const float4*)(x0_ + 4);                          \
    xa[(T) % 3][2] = *(const float4*)(x0_ + 32);                         \
    xa[(T) % 3][3] = *(const float4*)(x0_ + 36);                         \
    xa[(T) % 3][4] = *(const float4*)(x1_);                              \
    xa[(T) % 3][5] = *(const float4*)(x1_ + 4);                          \
    xa[(T) % 3][6] = *(const float4*)(x1_ + 32);                         \
    xa[(T) % 3][7] = *(const float4*)(x1_ + 36);                         \
  } while (0)

#define CVT8(dst, va, vb) do {                                           \
    dst[0] = (short)f2bf((va).x); dst[1] = (short)f2bf((va).y);          \
    dst[2] = (short)f2bf((va).z); dst[3] = (short)f2bf((va).w);          \
    dst[4] = (short)f2bf((vb).x); dst[5] = (short)f2bf((vb).y);          \
    dst[6] = (short)f2bf((vb).z); dst[7] = (short)f2bf((vb).w);          \
  } while (0)

#define MFMA_ __builtin_amdgcn_mfma_f32_16x16x32_bf16
#define KSTEP(T, KK, ALO, AHI) do {                                      \
    const int po_ = ((((KK) << 2) + q) ^ (lc & 7)) << 3;                 \
    const unsigned short* Bq_ = lds_B + (((((T) & 1) << 2) | w) << 12);  \
    v8s b0_ = *(const v8s*)(Bq_ + (lc << 6) + po_);                      \
    v8s b1_ = *(const v8s*)(Bq_ + 1024 + (lc << 6) + po_);               \
    v8s b2_ = *(const v8s*)(Bq_ + 2048 + (lc << 6) + po_);               \
    v8s b3_ = *(const v8s*)(Bq_ + 3072 + (lc << 6) + po_);               \
    acc1[0] = MFMA_(ALO, b0_, acc1[0], 0, 0, 0);                         \
    acc1[1] = MFMA_(ALO, b1_, acc1[1], 0, 0, 0);                         \
    acc1[2] = MFMA_(ALO, b2_, acc1[2], 0, 0, 0);                         \
    acc1[3] = MFMA_(ALO, b3_, acc1[3], 0, 0, 0);                         \
    acc1[4] = MFMA_(AHI, b0_, acc1[4], 0, 0, 0);                         \
    acc1[5] = MFMA_(AHI, b1_, acc1[5], 0, 0, 0);                         \
    acc1[6] = MFMA_(AHI, b2_, acc1[6], 0, 0, 0);                         \
    acc1[7] = MFMA_(AHI, b3_, acc1[7], 0, 0, 0);                         \
  } while (0)

// TILE: vmcnt(V) retires Xa(T)+B(T) exactly; compute; drain own ds_reads of
// buf[(T)&1] (lgkm); then issue B(T+2) into that buffer and Xa(T+3).
// Issue order B-before-Xa keeps younger Xa prefetches alive (vmcnt in-order).
#define TILE(T, V) do {                                                  \
    asm volatile("s_waitcnt vmcnt(" #V ")" ::: "memory");                \
    __builtin_amdgcn_sched_barrier(0);                                   \
    __builtin_amdgcn_s_setprio(1);                                       \
    v8s a00_, a01_, a10_, a11_;                                          \
    CVT8(a00_, xa[(T) % 3][0], xa[(T) % 3][1]);                          \
    CVT8(a01_, xa[(T) % 3][2], xa[(T) % 3][3]);                          \
    CVT8(a10_, xa[(T) % 3][4], xa[(T) % 3][5]);                          \
    CVT8(a11_, xa[(T) % 3][6], xa[(T) % 3][7]);                          \
    KSTEP(T, 0, a00_, a10_);                                             \
    KSTEP(T, 1, a01_, a11_);                                             \
    __builtin_amdgcn_s_setprio(0);                                       \
    asm volatile("s_waitcnt lgkmcnt(0)" ::: "memory");                   \
    __builtin_amdgcn_sched_barrier(0);                                   \
    if ((T) + 2 <= 15) STAGEB((T) + 2);                                  \
    if ((T) + 3 <= 15) XALOAD((T) + 3);                                  \
  } while (0)

  // ---- prologue (ledger order: Xa0, B0, Xa1, B1, Xa2) ----
  XALOAD(0);
  STAGEB(0);
  XALOAD(1);
  STAGEB(1);
  XALOAD(2);

  // ---- barrier-free k-loop; vmcnt: after-B(T) in flight = 24 (T<=13) ----
  TILE(0, 24);  TILE(1, 24);  TILE(2, 24);  TILE(3, 24);
  TILE(4, 24);  TILE(5, 24);  TILE(6, 24);  TILE(7, 24);
  TILE(8, 24);  TILE(9, 24);  TILE(10, 24); TILE(11, 24);
  TILE(12, 24); TILE(13, 24); TILE(14, 16); TILE(15, 0);

  // ---- GEMM2 proto loads issued now (stay in flight across GBAR) ----
  v8s pb[8];
  {
    const unsigned short* prow = protoB + ((w << 4) + lc) * D_PROJ + (q << 3);
#pragma unroll
    for (int kk = 0; kk < 8; ++kk)
      pb[kk] = *(const v8s*)(prow + (kk << 5));
  }

  GBAR();   // all waves done reading lds_B (each drained lgkm in TILE(15))

  // ---- Zc = Zraw - mu_p -> Z (aliases lds_B) + fp32 row norms ----
  unsigned short* lds_Z = lds_B;      // 8448 shorts = 16.5 KB
  float mu[4];
#pragma unroll
  for (int j = 0; j < 4; ++j) mu[j] = mu_p[(w << 6) + (j << 4) + lc];
#pragma unroll
  for (int rg = 0; rg < 2; ++rg) {
#pragma unroll
    for (int r = 0; r < 4; ++r) {
      const int row = (rg << 4) + (q << 2) + r;
      float s2 = 0.0f;
#pragma unroll
      for (int j = 0; j < 4; ++j) {
        const float v = acc1[rg * 4 + j][r] - mu[j];
        s2 += v * v;
        lds_Z[row * Z_STRIDE + (w << 6) + (j << 4) + lc] = f2bf(v);
      }
      s2 += __shfl_xor(s2, 1);
      s2 += __shfl_xor(s2, 2);
      s2 += __shfl_xor(s2, 4);
      s2 += __shfl_xor(s2, 8);
      if (lc == 0) lds_part[w][row] = s2;
    }
  }
  __syncthreads();
  if (t < BM) {
    const float n2 = lds_part[0][t] + lds_part[1][t] +
                     lds_part[2][t] + lds_part[3][t];
    const float nrm = sqrtf(n2);
    const float inv = 1.0f / fmaxf(nrm, 1e-12f);   // torch/jax normalize eps
    lds_inv[t] = inv;
    lds_z2[t]  = n2 * inv * inv;                   // == 1 unless degenerate
  }
  __syncthreads();

  // ---- GEMM2: dot(Zc, proto_c); wave w: 32 rows x protos w*16..+15 ----
  v4f acc2[2] = { (v4f)(0.0f), (v4f)(0.0f) };
#pragma unroll
  for (int kk = 0; kk < 8; ++kk) {
#pragma unroll
    for (int sr = 0; sr < 2; ++sr) {
      v8s za = *(const v8s*)(lds_Z + ((sr << 4) + lc) * Z_STRIDE +
                             (kk << 5) + (q << 3));
      acc2[sr] = MFMA_(za, pb[kk], acc2[sr], 0, 0, 0);
    }
  }

  // ---- epilogue: d^2 = ||Z||^2 + ||p||^2 - 2*dot*inv ; score = -sqrt(d^2) ----
  const int c  = (w << 4) + lc;
  const float pn = pnorm2[c];
#pragma unroll
  for (int sr = 0; sr < 2; ++sr) {
#pragma unroll
    for (int r = 0; r < 4; ++r) {
      const int row = (sr << 4) + (q << 2) + r;
      const float inv = lds_inv[row];
      const float d2  = lds_z2[row] + pn - 2.0f * acc2[sr][r] * inv;
      out[(row0 + row) * N_C + c] = -sqrtf(fmaxf(d2, 0.0f));
    }
  }
}

extern "C" void kernel_launch(void* const* d_in, const int* in_sizes, int n_in,
                              void* d_out, int out_size, void* d_ws, size_t ws_size,
                              hipStream_t stream) {
  const float* X      = (const float*)d_in[0];
  const float* protos = (const float*)d_in[1];
  const float* mean   = (const float*)d_in[2];
  const float* proj   = (const float*)d_in[3];
  float* out = (float*)d_out;

  unsigned short* projT  = (unsigned short*)d_ws;          // 256*1024 bf16 = 512 KB
  unsigned short* protoB = projT + D_PROJ * D_IN;          // 64*256  bf16 = 32 KB
  float*          pn2    = (float*)(protoB + N_C * D_PROJ);// 64 fp32
  float*          mup    = pn2 + N_C;                      // 256 fp32

  prep_kernel<<<96, 256, 0, stream>>>(proj, protos, mean, projT, protoB, pn2, mup);
  protonet_main<<<N_ROWS / BM, 256, 0, stream>>>(X, projT, protoB, pn2, mup, out);
}

// Round 12
// 126.646 us; speedup vs baseline: 1.1179x; 1.0879x over previous
//
#include <hip/hip_runtime.h>

// ============================================================================
// R12 = R9 (best measured: 114.7us) with the group-boundary convoy halved:
//   - A group 4 -> 8 tiles (32 KB single-buffered; 1 interior boundary);
//     GBARs 8 -> 2, conversion phases 3 -> 1. LDS ~97 KB, 1 block/CU (same
//     occupancy as R9 which also ran 1 block/CU at 81 KB).
//   - vmcnt ledger (hand-simulated): T0:8, T1:24, T2:24, T3-14:8, T15:0.
//     Xg1 issued after TILE(0) -> ~3-tile slack before forced retire at T3.
//   - __launch_bounds__(256,1): R9's ",2" capped VGPR=128 with no occupancy
//     gain (LDS-bound); xf group needs 64 VGPRs held across a group.
//   - T5 setprio(1) around MFMA (waves desync'd between barriers).
// Diagnosis R10/R11: A-per-wave-from-global refuted (4x A issue duplication,
// 16 VMEM/tile on critical path; 52-57us). Convoy-removal is the only lever
// that has ever correlated with improvement (R9's win).
// ============================================================================

#define D_IN   1024
#define D_PROJ 256
#define N_C    64
#define N_ROWS 16384
#define BM     32
#define BK     64
#define Z_STRIDE 264        // D_PROJ + 8 pad

typedef float v4f __attribute__((ext_vector_type(4)));
typedef short v8s __attribute__((ext_vector_type(8)));

__device__ inline unsigned short f2bf(float f) {
  unsigned int u = __float_as_uint(f);
  u = u + 0x7fffu + ((u >> 16) & 1u);   // round-to-nearest-even
  return (unsigned short)(u >> 16);
}

__device__ inline void async16(const void* g, void* s) {
  __builtin_amdgcn_global_load_lds(
      (const __attribute__((address_space(1))) unsigned int*)g,
      (__attribute__((address_space(3))) unsigned int*)s, 16, 0, 0);
}

// lgkm-only barrier: global/DMA loads stay in flight
#define GBAR() do {                                              \
  asm volatile("s_waitcnt lgkmcnt(0)" ::: "memory");             \
  __builtin_amdgcn_s_barrier();                                  \
  __builtin_amdgcn_sched_barrier(0);                             \
} while (0)

// ---------------------------------------------------------------------------
// Prep (unchanged): projT bf16 [256][1024], protoB bf16 [64][256], pnorm2[64],
// mu_p[256] = mean @ proj
// ---------------------------------------------------------------------------
__global__ __launch_bounds__(256) void prep_kernel(
    const float* __restrict__ proj,      // [1024][256]
    const float* __restrict__ protos,    // [64][256]
    const float* __restrict__ mean,      // [1024]
    unsigned short* __restrict__ projT,  // [256][1024]
    unsigned short* __restrict__ protoB, // [64][256]
    float* __restrict__ pnorm2,          // [64]
    float* __restrict__ mu_p)            // [256]
{
  __shared__ float tile[64][65];
  __shared__ float part[16][17];
  const int b = blockIdx.x;
  const int t = threadIdx.x;
  if (b < 64) {
    const int k0 = (b & 15) * 64, n0 = (b >> 4) * 64;
    const int r = t >> 4, c4 = (t & 15) * 4;
    for (int rr = r; rr < 64; rr += 16) {
      const float4 v = *(const float4*)(proj + (k0 + rr) * D_PROJ + n0 + c4);
      tile[rr][c4 + 0] = v.x; tile[rr][c4 + 1] = v.y;
      tile[rr][c4 + 2] = v.z; tile[rr][c4 + 3] = v.w;
    }
    __syncthreads();
    const int n = t >> 2, kc = (t & 3) * 16;
    unsigned short o[16];
#pragma unroll
    for (int i = 0; i < 16; ++i) o[i] = f2bf(tile[kc + i][n]);
    unsigned short* dst = projT + (n0 + n) * D_IN + k0 + kc;
#pragma unroll
    for (int i = 0; i < 4; ++i) {
      ushort4 s4 = { o[4*i+0], o[4*i+1], o[4*i+2], o[4*i+3] };
      *(ushort4*)(dst + 4*i) = s4;
    }
  } else if (b < 80) {
    const int w = t >> 6, l = t & 63;
    const int c = (b - 64) * 4 + w;                    // proto 0..63
    const float4 v = *(const float4*)(protos + c * D_PROJ + l * 4);
    float ss = v.x*v.x + v.y*v.y + v.z*v.z + v.w*v.w;
#pragma unroll
    for (int m = 1; m < 64; m <<= 1) ss += __shfl_xor(ss, m);
    if (l == 0) pnorm2[c] = ss;
    ushort4 o = { f2bf(v.x), f2bf(v.y), f2bf(v.z), f2bf(v.w) };
    *(ushort4*)(protoB + c * D_PROJ + l * 4) = o;
  } else {
    const int b2  = b - 80;
    const int col = b2 * 16 + (t & 15);
    const int ks  = t >> 4;
    float s = 0.0f;
    const int kb = ks * 64;
#pragma unroll 4
    for (int k = 0; k < 64; ++k)
      s = fmaf(mean[kb + k], proj[(kb + k) * D_PROJ + col], s);
    part[ks][t & 15] = s;
    __syncthreads();
    if (t < 16) {
      float acc = 0.0f;
#pragma unroll
      for (int i = 0; i < 16; ++i) acc += part[i][t];
      mu_p[b2 * 16 + t] = acc;
    }
  }
}

// ---------------------------------------------------------------------------
// Main: 32 rows/block, 512 blocks (1/CU), 256 threads (4 waves).
// Wave w: rows 0..31 x cols w*64..+63; B wave-private DMA double-buffer,
// wave-local counted vmcnt; A shared LDS in ONE 8-tile group per half
// (single interior boundary: GBAR, convert Xg1, GBAR).
// ---------------------------------------------------------------------------
__global__ __launch_bounds__(256, 1) void protonet_main(
    const float* __restrict__ X,               // [16384][1024]
    const unsigned short* __restrict__ projT,  // [256][1024] bf16
    const unsigned short* __restrict__ protoB, // [64][256]   bf16
    const float* __restrict__ pnorm2,          // [64]
    const float* __restrict__ mu_p,            // [256]
    float* __restrict__ out)                   // [16384][64]
{
  __shared__ unsigned short lds_B[32768];   // 64 KB: 2 bufs x 4 wave-quarters
  __shared__ unsigned short lds_A[16384];   // 32 KB: 8 k-tiles, swizzled
  __shared__ float lds_part[4][BM];
  __shared__ float lds_inv[BM];
  __shared__ float lds_z2[BM];

  const int t  = threadIdx.x;
  const int w  = t >> 6;        // wave 0..3
  const int l  = t & 63;
  const int q  = l >> 4;
  const int lc = l & 15;
  const int row0 = blockIdx.x * BM;

  // B DMA src: instr s covers projT rows w*64+s*8..+7; lane l -> +(l>>3);
  // phys chunk l&7 holds logical (l&7)^(row&7) via pre-swizzled source.
  const int bsrc0 = ((w << 6) + (l >> 3)) * D_IN + (((l & 7) ^ ((l >> 3) & 7)) << 3);

  // A staging: thread owns row ar (0..31), chunk aj (0..7) = 8 floats/tile
  const int ar = t >> 3;
  const int aj = t & 7;
  const float* xbase = X + (row0 + ar) * D_IN + (aj << 3);
  unsigned short* awr = lds_A + (ar << 6) + ((aj ^ (ar & 7)) << 3);

  float4 xf[16];       // one 8-tile group of X in flight (64 VGPR)
  v4f acc1[8];         // [rg*4+j]: rows rg*16.. x cols w*64+j*16..
#pragma unroll
  for (int j = 0; j < 8; ++j) acc1[j] = (v4f)(0.0f);

#define STAGEB(T) do {                                                    \
    _Pragma("unroll")                                                     \
    for (int s_ = 0; s_ < 8; ++s_)                                        \
      async16(projT + bsrc0 + s_ * (8 * D_IN) + (T) * BK,                 \
              lds_B + (((((T) & 1) << 2) | w) << 12) + (s_ << 9));        \
  } while (0)

// load 8 tiles of X (16 dwordx4) for group g (tiles g*8 .. g*8+7)
#define XLD_GROUP(g) do {                                                 \
    _Pragma("unroll")                                                     \
    for (int i_ = 0; i_ < 8; ++i_) {                                      \
      xf[2*i_]   = *(const float4*)(xbase + (((g)*8 + i_) << 6));         \
      xf[2*i_+1] = *(const float4*)(xbase + (((g)*8 + i_) << 6) + 4);     \
    }                                                                     \
  } while (0)

// convert current xf group -> A tiles 0..7 of lds_A
#define CVTWRA() do {                                                    \
    _Pragma("unroll")                                                    \
    for (int i_ = 0; i_ < 8; ++i_) {                                     \
      const float4 f0_ = xf[2*i_], f1_ = xf[2*i_+1];                     \
      v8s o_;                                                            \
      o_[0] = (short)f2bf(f0_.x); o_[1] = (short)f2bf(f0_.y);            \
      o_[2] = (short)f2bf(f0_.z); o_[3] = (short)f2bf(f0_.w);            \
      o_[4] = (short)f2bf(f1_.x); o_[5] = (short)f2bf(f1_.y);            \
      o_[6] = (short)f2bf(f1_.z); o_[7] = (short)f2bf(f1_.w);            \
      *(v8s*)(awr + (i_ << 11)) = o_;                                    \
    }                                                                    \
  } while (0)

#define MFMA_ __builtin_amdgcn_mfma_f32_16x16x32_bf16
#define COMPUTE(T) do {                                                  \
    const unsigned short* Ab_ = lds_A + (((T) & 7) << 11);               \
    const unsigned short* Bq_ = lds_B + (((((T) & 1) << 2) | w) << 12);  \
    _Pragma("unroll")                                                    \
    for (int kk_ = 0; kk_ < 2; ++kk_) {                                  \
      const int po_ = (((kk_ << 2) + q) ^ (lc & 7)) << 3;                \
      v8s a0_ = *(const v8s*)(Ab_ + (lc << 6) + po_);                    \
      v8s a1_ = *(const v8s*)(Ab_ + ((16 + lc) << 6) + po_);             \
      v8s b0_ = *(const v8s*)(Bq_ + (lc << 6) + po_);                    \
      v8s b1_ = *(const v8s*)(Bq_ + 1024 + (lc << 6) + po_);             \
      v8s b2_ = *(const v8s*)(Bq_ + 2048 + (lc << 6) + po_);             \
      v8s b3_ = *(const v8s*)(Bq_ + 3072 + (lc << 6) + po_);             \
      acc1[0] = MFMA_(a0_, b0_, acc1[0], 0, 0, 0);                       \
      acc1[1] = MFMA_(a0_, b1_, acc1[1], 0, 0, 0);                       \
      acc1[2] = MFMA_(a0_, b2_, acc1[2], 0, 0, 0);                       \
      acc1[3] = MFMA_(a0_, b3_, acc1[3], 0, 0, 0);                       \
      acc1[4] = MFMA_(a1_, b0_, acc1[4], 0, 0, 0);                       \
      acc1[5] = MFMA_(a1_, b1_, acc1[5], 0, 0, 0);                       \
      acc1[6] = MFMA_(a1_, b2_, acc1[6], 0, 0, 0);                       \
      acc1[7] = MFMA_(a1_, b3_, acc1[7], 0, 0, 0);                       \
    }                                                                    \
  } while (0)

// wave-local tile: vmcnt(V) retires through B(T); MFMA under setprio(1);
// drain own ds_reads (lgkm) before re-staging the buffer for B(T+2).
#define TILE(T, V) do {                                                  \
    asm volatile("s_waitcnt vmcnt(" #V ")" ::: "memory");                \
    __builtin_amdgcn_sched_barrier(0);                                   \
    __builtin_amdgcn_s_setprio(1);                                       \
    COMPUTE(T);                                                          \
    __builtin_amdgcn_s_setprio(0);                                       \
    asm volatile("s_waitcnt lgkmcnt(0)" ::: "memory");                   \
    __builtin_amdgcn_sched_barrier(0);                                   \
    if ((T) + 2 <= 15) STAGEB((T) + 2);                                  \
  } while (0)

  // ---- prologue: Xg0(16), B0(8), B1(8); convert g0 (retires Xg0); GBAR ----
  XLD_GROUP(0);
  STAGEB(0);
  STAGEB(1);
  CVTWRA();                 // compiler waits Xg0 regs only (B0,B1 in flight)
  GBAR();                   // A group-0 visible to all waves

  // ---- k-loop: 2 barriers total. vmcnt ledger (in-order, hand-simulated):
  //   T0: {B0,B1}=16, need B0 -> 8.  T0 issues B2; then Xg1(16) issued.
  //   T1: {B1,B2,Xg1}: need B1 -> leaves B2,Xg1? order B1<B2<Xg1 -> 24.
  //   T2: need B2 -> leaves Xg1,B3 -> 24.  T3: need B3 (younger than Xg1)
  //       -> retires Xg1 too -> 8.  T4..14: {B(T),B(T+1)} -> 8.  T15: 0.
  TILE(0, 8);
  XLD_GROUP(1);             // issued after B2: ~3-tile slack before T3 retire
  TILE(1, 24); TILE(2, 24); TILE(3, 8);
  TILE(4, 8);  TILE(5, 8);  TILE(6, 8);  TILE(7, 8);
  GBAR();                   // all waves done reading A group 0
  CVTWRA();                 // Xg1 regs already landed (retired by T3)
  GBAR();                   // A group-1 visible
  TILE(8, 8);  TILE(9, 8);  TILE(10, 8); TILE(11, 8);
  TILE(12, 8); TILE(13, 8); TILE(14, 8); TILE(15, 0);

  // ---- GEMM2 proto loads issued now (stay in flight across GBAR) ----
  v8s pb[8];
  {
    const unsigned short* prow = protoB + ((w << 4) + lc) * D_PROJ + (q << 3);
#pragma unroll
    for (int kk = 0; kk < 8; ++kk)
      pb[kk] = *(const v8s*)(prow + (kk << 5));
  }

  GBAR();   // all waves done with lds_B (each drained lgkm in TILE(15))

  // ---- Zc = Zraw - mu_p -> Z (aliases lds_B) + fp32 row norms ----
  unsigned short* lds_Z = lds_B;      // 8448 shorts = 16.5 KB
  float mu[4];
#pragma unroll
  for (int j = 0; j < 4; ++j) mu[j] = mu_p[(w << 6) + (j << 4) + lc];
#pragma unroll
  for (int rg = 0; rg < 2; ++rg) {
#pragma unroll
    for (int r = 0; r < 4; ++r) {
      const int row = (rg << 4) + (q << 2) + r;
      float s2 = 0.0f;
#pragma unroll
      for (int j = 0; j < 4; ++j) {
        const float v = acc1[rg * 4 + j][r] - mu[j];
        s2 += v * v;
        lds_Z[row * Z_STRIDE + (w << 6) + (j << 4) + lc] = f2bf(v);
      }
      s2 += __shfl_xor(s2, 1);
      s2 += __shfl_xor(s2, 2);
      s2 += __shfl_xor(s2, 4);
      s2 += __shfl_xor(s2, 8);
      if (lc == 0) lds_part[w][row] = s2;
    }
  }
  __syncthreads();
  if (t < BM) {
    const float n2 = lds_part[0][t] + lds_part[1][t] +
                     lds_part[2][t] + lds_part[3][t];
    const float nrm = sqrtf(n2);
    const float inv = 1.0f / fmaxf(nrm, 1e-12f);   // torch/jax normalize eps
    lds_inv[t] = inv;
    lds_z2[t]  = n2 * inv * inv;                   // == 1 unless degenerate
  }
  __syncthreads();

  // ---- GEMM2: dot(Zc, proto_c); wave w: 32 rows x protos w*16..+15 ----
  v4f acc2[2] = { (v4f)(0.0f), (v4f)(0.0f) };
#pragma unroll
  for (int kk = 0; kk < 8; ++kk) {
#pragma unroll
    for (int sr = 0; sr < 2; ++sr) {
      v8s za = *(const v8s*)(lds_Z + ((sr << 4) + lc) * Z_STRIDE +
                             (kk << 5) + (q << 3));
      acc2[sr] = MFMA_(za, pb[kk], acc2[sr], 0, 0, 0);
    }
  }

  // ---- epilogue: d^2 = ||Z||^2 + ||p||^2 - 2*dot*inv ; score = -sqrt(d^2) ----
  const int c  = (w << 4) + lc;
  const float pn = pnorm2[c];
#pragma unroll
  for (int sr = 0; sr < 2; ++sr) {
#pragma unroll
    for (int r = 0; r < 4; ++r) {
      const int row = (sr << 4) + (q << 2) + r;
      const float inv = lds_inv[row];
      const float d2  = lds_z2[row] + pn - 2.0f * acc2[sr][r] * inv;
      out[(row0 + row) * N_C + c] = -sqrtf(fmaxf(d2, 0.0f));
    }
  }
}

extern "C" void kernel_launch(void* const* d_in, const int* in_sizes, int n_in,
                              void* d_out, int out_size, void* d_ws, size_t ws_size,
                              hipStream_t stream) {
  const float* X      = (const float*)d_in[0];
  const float* protos = (const float*)d_in[1];
  const float* mean   = (const float*)d_in[2];
  const float* proj   = (const float*)d_in[3];
  float* out = (float*)d_out;

  unsigned short* projT  = (unsigned short*)d_ws;          // 256*1024 bf16 = 512 KB
  unsigned short* protoB = projT + D_PROJ * D_IN;          // 64*256  bf16 = 32 KB
  float*          pn2    = (float*)(protoB + N_C * D_PROJ);// 64 fp32
  float*          mup    = pn2 + N_C;                      // 256 fp32

  prep_kernel<<<96, 256, 0, stream>>>(proj, protos, mean, projT, protoB, pn2, mup);
  protonet_main<<<N_ROWS / BM, 256, 0, stream>>>(X, projT, protoB, pn2, mup, out);
}

// Round 13
// 116.441 us; speedup vs baseline: 1.2159x; 1.0876x over previous
//
#include <hip/hip_runtime.h>

// ============================================================================
// R13 = R9's verified schedule x2 TLP. Diagnosis R12: occupancy 9.9% (1 blk/
// CU, 4 waves/CU) explains the 27->43us regression; the series now fits
// "latency-bound, throughput ~ resident waves" (R9: 8 waves/CU ~27us).
// Change: 512-thr blocks (8 waves, wave w owns cols w*32), LDS exactly 80KB
// (B 2x32KB wave-sliced + A 16KB 4-tile groups, scratch aliased) -> 2 blk/CU
// -> 16 waves/CU (4/SIMD). Wave-private counted vmcnt (batch=4): ledger
// T0,1:8 T2,3:4 T4,5:8 T6,7:4 T8,9:8 T10-14:4 T15:0 (hand-simulated).
// ============================================================================

#define D_IN   1024
#define D_PROJ 256
#define N_C    64
#define N_ROWS 16384
#define BM     32
#define BK     64
#define Z_STRIDE 264        // D_PROJ + 8 pad

typedef float v4f __attribute__((ext_vector_type(4)));
typedef short v8s __attribute__((ext_vector_type(8)));

__device__ inline unsigned short f2bf(float f) {
  unsigned int u = __float_as_uint(f);
  u = u + 0x7fffu + ((u >> 16) & 1u);   // round-to-nearest-even
  return (unsigned short)(u >> 16);
}

__device__ inline void async16(const void* g, void* s) {
  __builtin_amdgcn_global_load_lds(
      (const __attribute__((address_space(1))) unsigned int*)g,
      (__attribute__((address_space(3))) unsigned int*)s, 16, 0, 0);
}

// lgkm-only barrier: global/DMA loads stay in flight
#define GBAR() do {                                              \
  asm volatile("s_waitcnt lgkmcnt(0)" ::: "memory");             \
  __builtin_amdgcn_s_barrier();                                  \
  __builtin_amdgcn_sched_barrier(0);                             \
} while (0)

// ---------------------------------------------------------------------------
// Prep (unchanged): projT bf16 [256][1024], protoB bf16 [64][256], pnorm2[64],
// mu_p[256] = mean @ proj
// ---------------------------------------------------------------------------
__global__ __launch_bounds__(256) void prep_kernel(
    const float* __restrict__ proj,      // [1024][256]
    const float* __restrict__ protos,    // [64][256]
    const float* __restrict__ mean,      // [1024]
    unsigned short* __restrict__ projT,  // [256][1024]
    unsigned short* __restrict__ protoB, // [64][256]
    float* __restrict__ pnorm2,          // [64]
    float* __restrict__ mu_p)            // [256]
{
  __shared__ float tile[64][65];
  __shared__ float part[16][17];
  const int b = blockIdx.x;
  const int t = threadIdx.x;
  if (b < 64) {
    const int k0 = (b & 15) * 64, n0 = (b >> 4) * 64;
    const int r = t >> 4, c4 = (t & 15) * 4;
    for (int rr = r; rr < 64; rr += 16) {
      const float4 v = *(const float4*)(proj + (k0 + rr) * D_PROJ + n0 + c4);
      tile[rr][c4 + 0] = v.x; tile[rr][c4 + 1] = v.y;
      tile[rr][c4 + 2] = v.z; tile[rr][c4 + 3] = v.w;
    }
    __syncthreads();
    const int n = t >> 2, kc = (t & 3) * 16;
    unsigned short o[16];
#pragma unroll
    for (int i = 0; i < 16; ++i) o[i] = f2bf(tile[kc + i][n]);
    unsigned short* dst = projT + (n0 + n) * D_IN + k0 + kc;
#pragma unroll
    for (int i = 0; i < 4; ++i) {
      ushort4 s4 = { o[4*i+0], o[4*i+1], o[4*i+2], o[4*i+3] };
      *(ushort4*)(dst + 4*i) = s4;
    }
  } else if (b < 80) {
    const int w = t >> 6, l = t & 63;
    const int c = (b - 64) * 4 + w;                    // proto 0..63
    const float4 v = *(const float4*)(protos + c * D_PROJ + l * 4);
    float ss = v.x*v.x + v.y*v.y + v.z*v.z + v.w*v.w;
#pragma unroll
    for (int m = 1; m < 64; m <<= 1) ss += __shfl_xor(ss, m);
    if (l == 0) pnorm2[c] = ss;
    ushort4 o = { f2bf(v.x), f2bf(v.y), f2bf(v.z), f2bf(v.w) };
    *(ushort4*)(protoB + c * D_PROJ + l * 4) = o;
  } else {
    const int b2  = b - 80;
    const int col = b2 * 16 + (t & 15);
    const int ks  = t >> 4;
    float s = 0.0f;
    const int kb = ks * 64;
#pragma unroll 4
    for (int k = 0; k < 64; ++k)
      s = fmaf(mean[kb + k], proj[(kb + k) * D_PROJ + col], s);
    part[ks][t & 15] = s;
    __syncthreads();
    if (t < 16) {
      float acc = 0.0f;
#pragma unroll
      for (int i = 0; i < 16; ++i) acc += part[i][t];
      mu_p[b2 * 16 + t] = acc;
    }
  }
}

// ---------------------------------------------------------------------------
// Main: 32 rows/block, 512 blocks (2/CU), 512 threads (8 waves, 16 waves/CU).
// Wave w: rows 0..31 x cols w*32..+31; B wave-private DMA double-buffer
// (2 bufs x 8 slices x 4 KB), wave-local counted vmcnt, batch = 4 instrs.
// A shared LDS, 4-tile groups, 2 lgkm-only GBARs per boundary (6 total).
// ---------------------------------------------------------------------------
__global__ __launch_bounds__(512, 4) void protonet_main(
    const float* __restrict__ X,               // [16384][1024]
    const unsigned short* __restrict__ projT,  // [256][1024] bf16
    const unsigned short* __restrict__ protoB, // [64][256]   bf16
    const float* __restrict__ pnorm2,          // [64]
    const float* __restrict__ mu_p,            // [256]
    float* __restrict__ out)                   // [16384][64]
{
  __shared__ unsigned short lds_B[32768];   // 64 KB: 2 bufs x 8 wave-slices(4KB)
  __shared__ unsigned short lds_A[8192];    // 16 KB: 4 k-tiles, swizzled
  // norm scratch aliases lds_A (dead after k-loop; written post-GBAR)
  float* lds_part = (float*)lds_A;          // [8][32]
  float* lds_inv  = (float*)lds_A + 256;    // [32]
  float* lds_z2   = (float*)lds_A + 288;    // [32]

  const int t  = threadIdx.x;
  const int w  = t >> 6;        // wave 0..7
  const int l  = t & 63;
  const int q  = l >> 4;
  const int lc = l & 15;
  const int row0 = blockIdx.x * BM;

  // B DMA src: instr s covers projT rows w*32+s*8..+7; lane l -> +(l>>3);
  // phys chunk l&7 holds logical (l&7)^(row&7) via pre-swizzled source.
  const int bsrc0 = ((w << 5) + (l >> 3)) * D_IN + (((l & 7) ^ ((l >> 3) & 7)) << 3);

  // A staging: thread owns row ar (0..31), float4 slot aj (0..15)
  const int ar = t >> 4;
  const int aj = t & 15;
  const float* xbase = X + (row0 + ar) * D_IN + (aj << 2);
  unsigned short* awr = lds_A + (ar << 6) +
      ((((aj >> 1) ^ (ar & 7)) << 3) | ((aj & 1) << 2));

  float4 xf[4];        // one 4-tile group of X in flight (16 VGPR)
  v4f acc1[4];         // [rg*2+j]: rows rg*16.. x cols w*32+j*16..
#pragma unroll
  for (int j = 0; j < 4; ++j) acc1[j] = (v4f)(0.0f);

#define STAGEB(T) do {                                                    \
    _Pragma("unroll")                                                     \
    for (int s_ = 0; s_ < 4; ++s_)                                        \
      async16(projT + bsrc0 + s_ * (8 * D_IN) + (T) * BK,                 \
              lds_B + (((((T) & 1) << 3) | w) << 11) + (s_ << 9));        \
  } while (0)

// load 4 tiles of X (one float4/thread/tile) for group g (tiles g*4..g*4+3)
#define XLD_GROUP(g) do {                                                 \
    _Pragma("unroll")                                                     \
    for (int i_ = 0; i_ < 4; ++i_)                                        \
      xf[i_] = *(const float4*)(xbase + (((g)*4 + i_) << 6));             \
  } while (0)

// convert current xf group -> A tiles 0..3 of lds_A
#define CVTWRA() do {                                                    \
    _Pragma("unroll")                                                    \
    for (int i_ = 0; i_ < 4; ++i_) {                                     \
      const float4 v_ = xf[i_];                                          \
      ushort4 o_ = { f2bf(v_.x), f2bf(v_.y), f2bf(v_.z), f2bf(v_.w) };   \
      *(ushort4*)(awr + (i_ << 11)) = o_;                                \
    }                                                                    \
  } while (0)

#define MFMA_ __builtin_amdgcn_mfma_f32_16x16x32_bf16
#define COMPUTE(T) do {                                                  \
    const unsigned short* Ab_ = lds_A + (((T) & 3) << 11);               \
    const unsigned short* Bq_ = lds_B + (((((T) & 1) << 3) | w) << 11);  \
    _Pragma("unroll")                                                    \
    for (int kk_ = 0; kk_ < 2; ++kk_) {                                  \
      const int po_ = (((kk_ << 2) + q) ^ (lc & 7)) << 3;                \
      v8s a0_ = *(const v8s*)(Ab_ + (lc << 6) + po_);                    \
      v8s a1_ = *(const v8s*)(Ab_ + ((16 + lc) << 6) + po_);             \
      v8s b0_ = *(const v8s*)(Bq_ + (lc << 6) + po_);                    \
      v8s b1_ = *(const v8s*)(Bq_ + 1024 + (lc << 6) + po_);             \
      acc1[0] = MFMA_(a0_, b0_, acc1[0], 0, 0, 0);                       \
      acc1[1] = MFMA_(a0_, b1_, acc1[1], 0, 0, 0);                       \
      acc1[2] = MFMA_(a1_, b0_, acc1[2], 0, 0, 0);                       \
      acc1[3] = MFMA_(a1_, b1_, acc1[3], 0, 0, 0);                       \
    }                                                                    \
  } while (0)

// wave-local tile: vmcnt(V) retires through B(T); MFMA under setprio(1);
// drain own ds_reads (lgkm) before re-staging the buffer for B(T+2).
#define TILE(T, V) do {                                                  \
    asm volatile("s_waitcnt vmcnt(" #V ")" ::: "memory");                \
    __builtin_amdgcn_sched_barrier(0);                                   \
    __builtin_amdgcn_s_setprio(1);                                       \
    COMPUTE(T);                                                          \
    __builtin_amdgcn_s_setprio(0);                                       \
    asm volatile("s_waitcnt lgkmcnt(0)" ::: "memory");                   \
    __builtin_amdgcn_sched_barrier(0);                                   \
    if ((T) + 2 <= 15) STAGEB((T) + 2);                                  \
  } while (0)

  // ---- prologue: Xg0(4), B0(4), B1(4), Xg1(4); cvt g0; GBAR ----
  XLD_GROUP(0);
  STAGEB(0);
  STAGEB(1);
  XLD_GROUP(1);
  CVTWRA();                 // compiler waits Xg0 regs only (B0,B1,Xg1 live)
  GBAR();                   // A group-0 visible to all waves

  // ---- k-loop; ledger (in-order, hand-simulated, batch=4):
  //  T0:[B0,B1,Xg1] need B0 -> 8   T1:[B1,Xg1,B2] -> 8
  //  T2:[Xg1,B2,B3] need B2 (retires Xg1) -> 4   T3:[B3,B4] -> 4
  //  boundary: GBAR, cvt Xg1 (landed at T2), GBAR, XLD_G2
  //  T4:[B4,B5,Xg2] -> 8  T5 -> 8  T6 (retires Xg2) -> 4  T7 -> 4
  //  boundary; T8 -> 8  T9 -> 8  T10 -> 4  T11 -> 4; boundary (no XLD)
  //  T12..14 -> 4;  T15 -> 0
  TILE(0, 8);  TILE(1, 8);  TILE(2, 4);  TILE(3, 4);
  GBAR(); CVTWRA(); GBAR(); XLD_GROUP(2);
  TILE(4, 8);  TILE(5, 8);  TILE(6, 4);  TILE(7, 4);
  GBAR(); CVTWRA(); GBAR(); XLD_GROUP(3);
  TILE(8, 8);  TILE(9, 8);  TILE(10, 4); TILE(11, 4);
  GBAR(); CVTWRA(); GBAR();
  TILE(12, 4); TILE(13, 4); TILE(14, 4); TILE(15, 0);

  // ---- GEMM2 proto loads issued now (stay in flight across GBAR) ----
  const int rw2 = w >> 2;       // 0..1: rows rw2*16..+15
  const int cw2 = w & 3;        // 0..3: protos cw2*16..+15
  v8s pb[8];
  {
    const unsigned short* prow = protoB + ((cw2 << 4) + lc) * D_PROJ + (q << 3);
#pragma unroll
    for (int kk = 0; kk < 8; ++kk)
      pb[kk] = *(const v8s*)(prow + (kk << 5));
  }

  GBAR();   // all waves done with lds_B (each drained lgkm in TILE(15))

  // ---- Zc = Zraw - mu_p -> Z (aliases lds_B) + fp32 row norms ----
  unsigned short* lds_Z = lds_B;      // 8448 shorts = 16.5 KB
  const float mu0 = mu_p[(w << 5) + lc];
  const float mu1 = mu_p[(w << 5) + 16 + lc];
#pragma unroll
  for (int rg = 0; rg < 2; ++rg) {
#pragma unroll
    for (int r = 0; r < 4; ++r) {
      const int row = (rg << 4) + (q << 2) + r;
      const float v0 = acc1[rg * 2 + 0][r] - mu0;
      const float v1 = acc1[rg * 2 + 1][r] - mu1;
      lds_Z[row * Z_STRIDE + (w << 5) + lc]      = f2bf(v0);
      lds_Z[row * Z_STRIDE + (w << 5) + 16 + lc] = f2bf(v1);
      float s2 = v0 * v0 + v1 * v1;
      s2 += __shfl_xor(s2, 1);
      s2 += __shfl_xor(s2, 2);
      s2 += __shfl_xor(s2, 4);
      s2 += __shfl_xor(s2, 8);
      if (lc == 0) lds_part[w * BM + row] = s2;
    }
  }
  __syncthreads();
  if (t < BM) {
    float n2 = 0.0f;
#pragma unroll
    for (int i = 0; i < 8; ++i) n2 += lds_part[i * BM + t];
    const float nrm = sqrtf(n2);
    const float inv = 1.0f / fmaxf(nrm, 1e-12f);   // torch/jax normalize eps
    lds_inv[t] = inv;
    lds_z2[t]  = n2 * inv * inv;                   // == 1 unless degenerate
  }
  __syncthreads();

  // ---- GEMM2: dot(Zc, proto_c); wave (rw2, cw2): 16 rows x 16 protos ----
  v4f acc2 = (v4f)(0.0f);
#pragma unroll
  for (int kk = 0; kk < 8; ++kk) {
    v8s za = *(const v8s*)(lds_Z + ((rw2 << 4) + lc) * Z_STRIDE +
                           (kk << 5) + (q << 3));
    acc2 = MFMA_(za, pb[kk], acc2, 0, 0, 0);
  }

  // ---- epilogue: d^2 = ||Z||^2 + ||p||^2 - 2*dot*inv ; score = -sqrt(d^2) ----
  const int c  = (cw2 << 4) + lc;
  const float pn = pnorm2[c];
#pragma unroll
  for (int r = 0; r < 4; ++r) {
    const int row = (rw2 << 4) + (q << 2) + r;
    const float inv = lds_inv[row];
    const float d2  = lds_z2[row] + pn - 2.0f * acc2[r] * inv;
    out[(row0 + row) * N_C + c] = -sqrtf(fmaxf(d2, 0.0f));
  }
}

extern "C" void kernel_launch(void* const* d_in, const int* in_sizes, int n_in,
                              void* d_out, int out_size, void* d_ws, size_t ws_size,
                              hipStream_t stream) {
  const float* X      = (const float*)d_in[0];
  const float* protos = (const float*)d_in[1];
  const float* mean   = (const float*)d_in[2];
  const float* proj   = (const float*)d_in[3];
  float* out = (float*)d_out;

  unsigned short* projT  = (unsigned short*)d_ws;          // 256*1024 bf16 = 512 KB
  unsigned short* protoB = projT + D_PROJ * D_IN;          // 64*256  bf16 = 32 KB
  float*          pn2    = (float*)(protoB + N_C * D_PROJ);// 64 fp32
  float*          mup    = pn2 + N_C;                      // 256 fp32

  prep_kernel<<<96, 256, 0, stream>>>(proj, protos, mean, projT, protoB, pn2, mup);
  protonet_main<<<N_ROWS / BM, 512, 0, stream>>>(X, projT, protoB, pn2, mup, out);
}